// Round 1
// baseline (928.325 us; speedup 1.0000x reference)
//
#include <hip/hip_runtime.h>
#include <hip/hip_bf16.h>
#include <stdint.h>

#define T_TOK 16384
#define HDIM  1024
#define FDIM  4096
#define NE    8
#define CAP   2560   // ceil(1.25 * 16384 / 8)

typedef __attribute__((ext_vector_type(8))) __bf16 bf16x8;
typedef __attribute__((ext_vector_type(4))) float  f32x4;

__device__ __forceinline__ unsigned short f2bf(float f) {
  union { float f; unsigned u; } c; c.f = f;
  unsigned u = c.u;
  return (unsigned short)((u + 0x7FFFu + ((u >> 16) & 1u)) >> 16);
}

__device__ __forceinline__ void gload_lds16(const void* g, void* lds) {
  __builtin_amdgcn_global_load_lds((const __attribute__((address_space(1))) void*)g,
                                   (__attribute__((address_space(3))) void*)lds,
                                   16, 0, 0);
}

// ---------------- transpose + fp32->bf16 convert: in (E,R,Cc) f32 -> out (E,Cc,R) bf16
__global__ __launch_bounds__(256)
void transpose_cvt(const float* __restrict__ in, unsigned short* __restrict__ out,
                   int R, int Cc) {
  __shared__ unsigned short tile[64][68];
  int e  = blockIdx.z;
  int rb = blockIdx.y << 6, cb = blockIdx.x << 6;
  const float* inp = in + (size_t)e * R * Cc;
  unsigned short* op = out + (size_t)e * R * Cc;
  int lc  = threadIdx.x & 63;
  int lr0 = threadIdx.x >> 6;
#pragma unroll
  for (int rr = 0; rr < 64; rr += 4) {
    int r = rr + lr0;
    float v = inp[(size_t)(rb + r) * Cc + cb + lc];
    tile[lc][r] = f2bf(v);
  }
  __syncthreads();
  int c0 = threadIdx.x >> 3;
  int h0 = (threadIdx.x & 7) << 3;
#pragma unroll
  for (int cc = 0; cc < 64; cc += 32) {
    int c = cc + c0;
    uint2 v0 = *(const uint2*)&tile[c][h0];
    uint2 v1 = *(const uint2*)&tile[c][h0 + 4];
    uint4 v; v.x = v0.x; v.y = v0.y; v.z = v1.x; v.w = v1.y;
    *(uint4*)(op + (size_t)(cb + c) * R + rb + h0) = v;
  }
}

// ---------------- router: 1 wave per token, fp32 logits, top-2
__global__ __launch_bounds__(256)
void router_kernel(const float* __restrict__ tokens, const float* __restrict__ wr,
                   int* __restrict__ topsel, float* __restrict__ wts) {
  int lane = threadIdx.x & 63;
  int t = (blockIdx.x << 2) + (threadIdx.x >> 6);
  const float* tok = tokens + (size_t)t * HDIM;
  float acc[8];
#pragma unroll
  for (int i = 0; i < 8; ++i) acc[i] = 0.f;
#pragma unroll
  for (int j = 0; j < 4; ++j) {
    int h0 = j * 256 + lane * 4;
    float4 tv = *(const float4*)(tok + h0);
    const float* w = wr + (size_t)h0 * 8;
#pragma unroll
    for (int q = 0; q < 4; ++q) {
      float xv = ((const float*)&tv)[q];
      float4 wa = *(const float4*)(w + q * 8);
      float4 wb = *(const float4*)(w + q * 8 + 4);
      acc[0] += xv * wa.x; acc[1] += xv * wa.y; acc[2] += xv * wa.z; acc[3] += xv * wa.w;
      acc[4] += xv * wb.x; acc[5] += xv * wb.y; acc[6] += xv * wb.z; acc[7] += xv * wb.w;
    }
  }
#pragma unroll
  for (int off = 1; off < 64; off <<= 1) {
#pragma unroll
    for (int i = 0; i < 8; ++i) acc[i] += __shfl_xor(acc[i], off, 64);
  }
  if (lane == 0) {
    int e0 = 0; float v0 = acc[0];
#pragma unroll
    for (int i = 1; i < 8; ++i) if (acc[i] > v0) { v0 = acc[i]; e0 = i; }
    int e1 = -1; float v1 = -3.4e38f;
#pragma unroll
    for (int i = 0; i < 8; ++i) if (i != e0 && acc[i] > v1) { v1 = acc[i]; e1 = i; }
    float w0 = 1.f / (1.f + __expf(v1 - v0));
    topsel[t * 2] = e0; topsel[t * 2 + 1] = e1;
    wts[t * 2] = w0;    wts[t * 2 + 1] = 1.f - w0;
  }
}

// ---------------- dispatch: ordered ranks per (k,e), capacity drop
__global__ void dispatch_kernel(const int* __restrict__ topsel, int* __restrict__ slot,
                                int* __restrict__ src_tok) {
  int k = blockIdx.x >> 3, e = blockIdx.x & 7;
  int lane = threadIdx.x;  // 64 threads
  unsigned long long lmask = (lane == 0) ? 0ull : (~0ull >> (64 - lane));
  int base = 0;
  if (k == 1) {
    for (int t0 = 0; t0 < T_TOK; t0 += 64) {
      int ch = topsel[(t0 + lane) * 2];
      base += __popcll(__ballot(ch == e));
    }
  }
  for (int t0 = 0; t0 < T_TOK; t0 += 64) {
    int t = t0 + lane;
    int ch = topsel[t * 2 + k];
    unsigned long long m = __ballot(ch == e);
    if (ch == e) {
      int r = base + __popcll(m & lmask);
      if (r < CAP) { slot[t * 2 + k] = r; src_tok[e * CAP + r] = t; }
      else         { slot[t * 2 + k] = -1; }
    }
    base += __popcll(m);
  }
}

// ---------------- gather tokens -> bf16 x (E*CAP, HDIM); zero unfilled slots
__global__ __launch_bounds__(128)
void gather_x(const float* __restrict__ tokens, const int* __restrict__ src_tok,
              unsigned short* __restrict__ x) {
  int s = blockIdx.x;
  int t = src_tok[s];
  unsigned short* xr = x + (size_t)s * HDIM + threadIdx.x * 8;
  uint4 v = {0u, 0u, 0u, 0u};
  if (t >= 0) {
    const float* tr = tokens + (size_t)t * HDIM + threadIdx.x * 8;
    float4 a = *(const float4*)tr;
    float4 b = *(const float4*)(tr + 4);
    v.x = (unsigned)f2bf(a.x) | ((unsigned)f2bf(a.y) << 16);
    v.y = (unsigned)f2bf(a.z) | ((unsigned)f2bf(a.w) << 16);
    v.z = (unsigned)f2bf(b.x) | ((unsigned)f2bf(b.y) << 16);
    v.w = (unsigned)f2bf(b.z) | ((unsigned)f2bf(b.w) << 16);
  }
  *(uint4*)xr = v;
}

// ---------------- GEMM1: h = silu(x@Wg) * (x@Wu), dual-B fused, bf16 out
__global__ __launch_bounds__(512, 2)
void gemm1(const unsigned short* __restrict__ x, const unsigned short* __restrict__ wgT,
           const unsigned short* __restrict__ wuT, unsigned short* __restrict__ h) {
  __shared__ unsigned short As [128 * 32];
  __shared__ unsigned short Bgs[128 * 32];
  __shared__ unsigned short Bus[128 * 32];
  int e = blockIdx.z;
  const unsigned short* Ae = x   + (size_t)e * CAP  * HDIM + (size_t)blockIdx.y * 128 * HDIM;
  const unsigned short* Bg = wgT + (size_t)e * FDIM * HDIM + (size_t)blockIdx.x * 128 * HDIM;
  const unsigned short* Bu = wuT + (size_t)e * FDIM * HDIM + (size_t)blockIdx.x * 128 * HDIM;
  int tid = threadIdx.x, lane = tid & 63, wid = tid >> 6;
  int wr = (wid >> 1) * 32, wc = (wid & 1) * 64;
  int srow = tid >> 2, scol = (tid & 3) * 8;
  size_t goff = (size_t)srow * HDIM + scol;
  int loff = srow * 32 + scol;
  int fr = lane & 15, fk = (lane >> 4) * 8;
  f32x4 accg[2][4], accu[2][4];
#pragma unroll
  for (int m = 0; m < 2; ++m)
#pragma unroll
    for (int n = 0; n < 4; ++n) {
      accg[m][n] = (f32x4){0.f, 0.f, 0.f, 0.f};
      accu[m][n] = (f32x4){0.f, 0.f, 0.f, 0.f};
    }
  for (int kt = 0; kt < HDIM; kt += 32) {
    __syncthreads();
    gload_lds16(Ae + goff + kt, As  + loff);
    gload_lds16(Bg + goff + kt, Bgs + loff);
    gload_lds16(Bu + goff + kt, Bus + loff);
    __syncthreads();
    bf16x8 af[2], bgf[4], buf_[4];
#pragma unroll
    for (int m = 0; m < 2; ++m)
      af[m] = *(const bf16x8*)(As + (wr + m * 16 + fr) * 32 + fk);
#pragma unroll
    for (int n = 0; n < 4; ++n) {
      bgf[n]  = *(const bf16x8*)(Bgs + (wc + n * 16 + fr) * 32 + fk);
      buf_[n] = *(const bf16x8*)(Bus + (wc + n * 16 + fr) * 32 + fk);
    }
#pragma unroll
    for (int m = 0; m < 2; ++m)
#pragma unroll
      for (int n = 0; n < 4; ++n) {
        accg[m][n] = __builtin_amdgcn_mfma_f32_16x16x32_bf16(af[m], bgf[n],  accg[m][n], 0, 0, 0);
        accu[m][n] = __builtin_amdgcn_mfma_f32_16x16x32_bf16(af[m], buf_[n], accu[m][n], 0, 0, 0);
      }
  }
  unsigned short* hp = h + (size_t)e * CAP * FDIM
                         + (size_t)(blockIdx.y * 128 + wr + (lane >> 4) * 4) * FDIM
                         + blockIdx.x * 128 + wc + fr;
#pragma unroll
  for (int m = 0; m < 2; ++m)
#pragma unroll
    for (int n = 0; n < 4; ++n)
#pragma unroll
      for (int v = 0; v < 4; ++v) {
        float g = accg[m][n][v], u = accu[m][n][v];
        float s = g / (1.f + __expf(-g));
        hp[(size_t)(m * 16 + v) * FDIM + n * 16] = f2bf(s * u);
      }
}

// ---------------- GEMM2: y = h @ Wd, fp32 out
__global__ __launch_bounds__(512, 2)
void gemm2(const unsigned short* __restrict__ h, const unsigned short* __restrict__ wdT,
           float* __restrict__ y) {
  __shared__ unsigned short As[128 * 32];
  __shared__ unsigned short Bs[128 * 32];
  int e = blockIdx.z;
  const unsigned short* Ae = h   + (size_t)e * CAP  * FDIM + (size_t)blockIdx.y * 128 * FDIM;
  const unsigned short* Be = wdT + (size_t)e * HDIM * FDIM + (size_t)blockIdx.x * 128 * FDIM;
  int tid = threadIdx.x, lane = tid & 63, wid = tid >> 6;
  int wr = (wid >> 1) * 32, wc = (wid & 1) * 64;
  int srow = tid >> 2, scol = (tid & 3) * 8;
  size_t goff = (size_t)srow * FDIM + scol;
  int loff = srow * 32 + scol;
  int fr = lane & 15, fk = (lane >> 4) * 8;
  f32x4 acc[2][4];
#pragma unroll
  for (int m = 0; m < 2; ++m)
#pragma unroll
    for (int n = 0; n < 4; ++n) acc[m][n] = (f32x4){0.f, 0.f, 0.f, 0.f};
  for (int kt = 0; kt < FDIM; kt += 32) {
    __syncthreads();
    gload_lds16(Ae + goff + kt, As + loff);
    gload_lds16(Be + (size_t)srow * FDIM + kt + scol, Bs + loff);
    __syncthreads();
    bf16x8 af[2], bf_[4];
#pragma unroll
    for (int m = 0; m < 2; ++m)
      af[m] = *(const bf16x8*)(As + (wr + m * 16 + fr) * 32 + fk);
#pragma unroll
    for (int n = 0; n < 4; ++n)
      bf_[n] = *(const bf16x8*)(Bs + (wc + n * 16 + fr) * 32 + fk);
#pragma unroll
    for (int m = 0; m < 2; ++m)
#pragma unroll
      for (int n = 0; n < 4; ++n)
        acc[m][n] = __builtin_amdgcn_mfma_f32_16x16x32_bf16(af[m], bf_[n], acc[m][n], 0, 0, 0);
  }
  float* yp = y + ((size_t)e * CAP + blockIdx.y * 128 + wr + (lane >> 4) * 4) * HDIM
                + blockIdx.x * 128 + wc + fr;
#pragma unroll
  for (int m = 0; m < 2; ++m)
#pragma unroll
    for (int n = 0; n < 4; ++n)
#pragma unroll
      for (int v = 0; v < 4; ++v)
        yp[(size_t)(m * 16 + v) * HDIM + n * 16] = acc[m][n][v];
}

// ---------------- combine: out[t] = sum_k w_k * y[e_k, slot_k]
__global__ __launch_bounds__(256)
void combine_kernel(const float* __restrict__ y, const int* __restrict__ topsel,
                    const int* __restrict__ slot, const float* __restrict__ wts,
                    float* __restrict__ out) {
  int t = blockIdx.x;
  int i = threadIdx.x * 4;
  float4 s = {0.f, 0.f, 0.f, 0.f};
#pragma unroll
  for (int k = 0; k < 2; ++k) {
    int sl = slot[t * 2 + k];
    if (sl >= 0) {
      int e = topsel[t * 2 + k];
      float w = wts[t * 2 + k];
      float4 v = *(const float4*)(y + ((size_t)e * CAP + sl) * HDIM + i);
      s.x += w * v.x; s.y += w * v.y; s.z += w * v.z; s.w += w * v.w;
    }
  }
  *(float4*)(out + (size_t)t * HDIM + i) = s;
}

extern "C" void kernel_launch(void* const* d_in, const int* in_sizes, int n_in,
                              void* d_out, int out_size, void* d_ws, size_t ws_size,
                              hipStream_t stream) {
  const float* tokens   = (const float*)d_in[0];
  const float* w_router = (const float*)d_in[1];
  const float* w_gate   = (const float*)d_in[2];
  const float* w_up     = (const float*)d_in[3];
  const float* w_down   = (const float*)d_in[4];
  float* out = (float*)d_out;
  char* ws = (char*)d_ws;

  const size_t WB = (size_t)NE * FDIM * HDIM * 2;   // 64 MiB per weight tensor (bf16)
  const size_t XB = (size_t)NE * CAP * HDIM * 2;
  const size_t HB = (size_t)NE * CAP * FDIM * 2;
  unsigned short* wgT  = (unsigned short*)(ws);
  unsigned short* wuT  = (unsigned short*)(ws + WB);
  unsigned short* wdT  = (unsigned short*)(ws + 2 * WB);
  unsigned short* xbuf = (unsigned short*)(ws + 3 * WB);
  unsigned short* hbuf = (unsigned short*)(ws + 3 * WB + XB);
  float* ybuf = (float*)(ws);                        // aliases wgT/wuT (dead after gemm1)
  char* tail = ws + 3 * WB + XB + HB;
  int*   topsel  = (int*)tail;
  float* wtsv    = (float*)(tail + (size_t)T_TOK * 2 * 4);
  int*   slotv   = (int*)(tail + (size_t)T_TOK * 2 * 8);
  int*   src_tok = (int*)(tail + (size_t)T_TOK * 2 * 12);

  hipMemsetAsync(src_tok, 0xFF, (size_t)NE * CAP * 4, stream);

  transpose_cvt<<<dim3(FDIM / 64, HDIM / 64, NE), 256, 0, stream>>>(w_gate, wgT, HDIM, FDIM);
  transpose_cvt<<<dim3(FDIM / 64, HDIM / 64, NE), 256, 0, stream>>>(w_up,   wuT, HDIM, FDIM);
  transpose_cvt<<<dim3(HDIM / 64, FDIM / 64, NE), 256, 0, stream>>>(w_down, wdT, FDIM, HDIM);

  router_kernel<<<T_TOK / 4, 256, 0, stream>>>(tokens, w_router, topsel, wtsv);
  dispatch_kernel<<<16, 64, 0, stream>>>(topsel, slotv, src_tok);
  gather_x<<<NE * CAP, 128, 0, stream>>>(tokens, src_tok, xbuf);

  gemm1<<<dim3(FDIM / 128, CAP / 128, NE), 512, 0, stream>>>(xbuf, wgT, wuT, hbuf);
  gemm2<<<dim3(HDIM / 128, CAP / 128, NE), 512, 0, stream>>>(hbuf, wdT, ybuf);

  combine_kernel<<<T_TOK, 256, 0, stream>>>(ybuf, topsel, slotv, wtsv, out);
}